// Round 10
// baseline (105.536 us; speedup 1.0000x reference)
//
#include <hip/hip_runtime.h>

#define N 64
#define ITERS 50
#define TEMP 12.5f
#define WEPS 1e-5f
#define QDIM 75
#define WDIM 5

typedef float v2f __attribute__((ext_vector_type(2)));

// guaranteed packed fp32 FMA (2 MACs / instruction, VOP3P)
static __device__ __forceinline__ v2f pkfma(v2f a, v2f b, v2f c) {
    v2f d;
    asm("v_pk_fma_f32 %0, %1, %2, %3" : "=v"(d) : "v"(a), "v"(b), "v"(c));
    return d;
}

// quad_perm butterfly within aligned 4-lane quads (VALU pipe)
#define DPP_XOR1(x) __int_as_float(__builtin_amdgcn_update_dpp(0, __float_as_int(x), 0xB1, 0xF, 0xF, true))
#define DPP_XOR2(x) __int_as_float(__builtin_amdgcn_update_dpp(0, __float_as_int(x), 0x4E, 0xF, 0xF, true))

__device__ __forceinline__ float waveReduceSum(float x) {
#pragma unroll
    for (int off = 32; off; off >>= 1) x += __shfl_xor(x, off, 64);
    return x;
}

// TWO waves per problem (3000 waves total -> 2.93/SIMD TLP so the per-phase
// dependent chain of one wave hides under the others'). Thread t owns a 2x16
// tile of K: rows 2g..2g+1 (g=t>>2), cols 16s..16s+15 (s=t&3), plus the
// transposed tile for the K^T phase. Per phase: 4 ds_read_b128 + 16 pk-FMA +
// quad DPP butterfly + (s==0) one ds_write_b64. LDS volume/phase = 8KB.
__global__ __launch_bounds__(128, 1) void emd_pk2(
    const float* __restrict__ sim,   // [B, 64, 64]
    const float* __restrict__ w1,    // [B, N]
    const float* __restrict__ w2,    // [E, W, Q, N] (transposed Q/W)
    float* __restrict__ out,         // [B]
    int B)
{
    __shared__ __align__(16) float U[N], V[N], A[N], Bm[N];
    __shared__ float Wred[2];

    const int t    = threadIdx.x;
    const int lane = t & 63;
    const int wv   = t >> 6;
    const int g    = t >> 2;      // row-pair base 2g (0..31 -> rows 0..63)
    const int s    = t & 3;       // col-segment base 16s
    const int b    = blockIdx.x;
    const float* gm = sim + (size_t)b * N * N;

    // ---- marginals: wave 0 does A + V-init, wave 1 does Bm ----
    if (wv == 0) {
        float a = w1[(size_t)b * N + lane];
        a = fmaxf(a, 0.0f) + WEPS;
        a *= (float)N / waveReduceSum(a);
        A[lane] = a;
        V[lane] = 1.0f;
    } else {
        const int e  = b / (QDIM * WDIM);
        const int rm = b % (QDIM * WDIM);
        const int q  = rm / WDIM, w = rm % WDIM;
        float gg = w2[((((size_t)e * WDIM + w) * QDIM) + q) * N + lane];
        gg = fmaxf(gg, 0.0f) + WEPS;
        gg *= (float)N / waveReduceSum(gg);
        Bm[lane] = gg;
    }

    // ---- K fragments from global (16KB matrix, L1/L2 resident) ----
    // Kr2[k][m] = {K[2g+k][16s+2m], K[2g+k][16s+2m+1]}
    // Kc2[k][m] = {K[16s+2m][2g+k], K[16s+2m+1][2g+k]},  K = exp(20*(sim-1))
    v2f Kr2[2][8], Kc2[2][8];
#pragma unroll
    for (int k = 0; k < 2; ++k)
#pragma unroll
        for (int m = 0; m < 4; ++m) {
            float4 x = *(const float4*)(gm + (2 * g + k) * N + 16 * s + 4 * m);
            Kr2[k][2 * m + 0][0] = __expf((x.x - 1.0f) * 20.0f);
            Kr2[k][2 * m + 0][1] = __expf((x.y - 1.0f) * 20.0f);
            Kr2[k][2 * m + 1][0] = __expf((x.z - 1.0f) * 20.0f);
            Kr2[k][2 * m + 1][1] = __expf((x.w - 1.0f) * 20.0f);
        }
#pragma unroll
    for (int j = 0; j < 16; ++j) {
        float2 x = *(const float2*)(gm + (16 * s + j) * N + 2 * g);
        Kc2[0][j >> 1][j & 1] = __expf((x.x - 1.0f) * 20.0f);
        Kc2[1][j >> 1][j & 1] = __expf((x.y - 1.0f) * 20.0f);
    }
    // opaque pin: forbid sinking/remat of the exp chains into the loop
#pragma unroll
    for (int k = 0; k < 2; ++k)
#pragma unroll
        for (int m = 0; m < 8; ++m) {
            asm volatile("" : "+v"(Kr2[k][m]));
            asm volatile("" : "+v"(Kc2[k][m]));
        }

    __syncthreads();
    const float2 a2 = *(const float2*)&A[2 * g];    // a[2g], a[2g+1]
    const float2 b2 = *(const float2*)&Bm[2 * g];   // b[2g], b[2g+1]

#pragma unroll 1
    for (int it = 0; it < ITERS; ++it) {
        // ---- u-phase: u[r] = a[r]/sum_c K[r][c] v[c] ----
        {
            const float4* V4 = (const float4*)&V[16 * s];
            float4 x0 = V4[0], x1 = V4[1], x2 = V4[2], x3 = V4[3];
            v2f vv[8] = {{x0.x, x0.y}, {x0.z, x0.w}, {x1.x, x1.y}, {x1.z, x1.w},
                         {x2.x, x2.y}, {x2.z, x2.w}, {x3.x, x3.y}, {x3.z, x3.w}};
            v2f a00 = {0, 0}, a01 = {0, 0}, a10 = {0, 0}, a11 = {0, 0};
#pragma unroll
            for (int m = 0; m < 4; ++m) {
                a00 = pkfma(Kr2[0][2 * m + 0], vv[2 * m + 0], a00);
                a01 = pkfma(Kr2[0][2 * m + 1], vv[2 * m + 1], a01);
                a10 = pkfma(Kr2[1][2 * m + 0], vv[2 * m + 0], a10);
                a11 = pkfma(Kr2[1][2 * m + 1], vv[2 * m + 1], a11);
            }
            float r0 = (a00[0] + a00[1]) + (a01[0] + a01[1]);
            float r1 = (a10[0] + a10[1]) + (a11[0] + a11[1]);
            r0 += DPP_XOR1(r0);  r1 += DPP_XOR1(r1);
            r0 += DPP_XOR2(r0);  r1 += DPP_XOR2(r1);
            if (s == 0) {
                float2 uo;
                uo.x = a2.x * __builtin_amdgcn_rcpf(r0);
                uo.y = a2.y * __builtin_amdgcn_rcpf(r1);
                *(float2*)&U[2 * g] = uo;
            }
        }
        __syncthreads();

        // ---- v-phase: v[c] = b[c]/sum_i K[i][c] u[i] ----
        {
            const float4* U4 = (const float4*)&U[16 * s];
            float4 x0 = U4[0], x1 = U4[1], x2 = U4[2], x3 = U4[3];
            v2f uu[8] = {{x0.x, x0.y}, {x0.z, x0.w}, {x1.x, x1.y}, {x1.z, x1.w},
                         {x2.x, x2.y}, {x2.z, x2.w}, {x3.x, x3.y}, {x3.z, x3.w}};
            v2f a00 = {0, 0}, a01 = {0, 0}, a10 = {0, 0}, a11 = {0, 0};
#pragma unroll
            for (int m = 0; m < 4; ++m) {
                a00 = pkfma(Kc2[0][2 * m + 0], uu[2 * m + 0], a00);
                a01 = pkfma(Kc2[0][2 * m + 1], uu[2 * m + 1], a01);
                a10 = pkfma(Kc2[1][2 * m + 0], uu[2 * m + 0], a10);
                a11 = pkfma(Kc2[1][2 * m + 1], uu[2 * m + 1], a11);
            }
            float r0 = (a00[0] + a00[1]) + (a01[0] + a01[1]);
            float r1 = (a10[0] + a10[1]) + (a11[0] + a11[1]);
            r0 += DPP_XOR1(r0);  r1 += DPP_XOR1(r1);
            r0 += DPP_XOR2(r0);  r1 += DPP_XOR2(r1);
            if (s == 0) {
                float2 vo;
                vo.x = b2.x * __builtin_amdgcn_rcpf(r0);
                vo.y = b2.y * __builtin_amdgcn_rcpf(r1);
                *(float2*)&V[2 * g] = vo;
            }
        }
        __syncthreads();
    }

    // ---- score = sum_ij u_i K_ij sim_ij v_j; sim = 1 + log2(K)*ln2/20 ----
    {
        const float2 u2 = *(const float2*)&U[2 * g];
        const float4* V4 = (const float4*)&V[16 * s];
        float4 x0 = V4[0], x1 = V4[1], x2 = V4[2], x3 = V4[3];
        float vj[16] = {x0.x, x0.y, x0.z, x0.w, x1.x, x1.y, x1.z, x1.w,
                        x2.x, x2.y, x2.z, x2.w, x3.x, x3.y, x3.z, x3.w};
        const float c = 0.69314718056f / 20.0f;
        float p = 0.0f;
#pragma unroll
        for (int k = 0; k < 2; ++k) {
            float rs = 0.0f;
#pragma unroll
            for (int j = 0; j < 16; ++j) {
                float kk = Kr2[k][j >> 1][j & 1];
                float sv = fmaf(__log2f(kk), c, 1.0f);   // sim_ij
                rs = fmaf(kk * sv, vj[j], rs);
            }
            p = fmaf(k ? u2.y : u2.x, rs, p);
        }
        float ws = waveReduceSum(p);
        if (lane == 0) Wred[wv] = ws;
    }
    __syncthreads();
    if (t == 0) out[b] = (Wred[0] + Wred[1]) * (TEMP / (float)N);
}

extern "C" void kernel_launch(void* const* d_in, const int* in_sizes, int n_in,
                              void* d_out, int out_size, void* d_ws, size_t ws_size,
                              hipStream_t stream) {
    const float* sim = (const float*)d_in[0];
    const float* w1  = (const float*)d_in[1];
    const float* w2  = (const float*)d_in[2];
    float* out       = (float*)d_out;
    const int B = in_sizes[0] / (N * N);   // 1500
    emd_pk2<<<B, 128, 0, stream>>>(sim, w1, w2, out, B);
}